// Round 6
// baseline (54.098 us; speedup 1.0000x reference)
//
#include <hip/hip_runtime.h>
#include <hip/hip_bf16.h>
#include <math.h>

typedef __attribute__((ext_vector_type(8))) short short8;
typedef __attribute__((ext_vector_type(4))) float f32x4;

#define T_SEQ 2048
#define NVOC 42
#define REP 5   // diagnostic repeat: idempotent re-execution to surface k_main in rocprof top-5

// ws float offsets
#define OFF_TAU 0        // 42*43 = 1806 f32
#define OFF_WB  1808     // u16 region: 12288 u16 ([8 n][16 col][96 k] bf16) = 6144 f32 -> 7952
#define OFF_HB  7952     // u16 region: 6144 u16 ([12 frag][64 lane][8] bf16) = 3072 f32 -> 11024

static __device__ __forceinline__ short f2b(float x){
  __hip_bfloat16 h = __float2bfloat16(x);
  return *reinterpret_cast<short*>(&h);
}

// Fused precompute (identical to round 5).
__global__ __launch_bounds__(256) void k_pre(const float* __restrict__ emb,
    const float* __restrict__ w1, const float* __restrict__ b1,
    const float* __restrict__ w2, const float* __restrict__ b2,
    const float* __restrict__ wv_w, const float* __restrict__ wv_b,
    const float* __restrict__ mg_w, const float* __restrict__ mg_b,
    const float* __restrict__ head_w, float* __restrict__ ws){
  __shared__ __align__(16) float sm[5376];
  int blk = blockIdx.x, tid = threadIdx.x;
  ushort* wbu = (ushort*)(ws + OFF_WB);
  if (blk < 42){
    int a = blk;
    {
      float4* d4 = (float4*)sm;
      const float4* e4 = (const float4*)emb;
      for (int i = tid; i < 1344; i += 256) d4[i] = e4[i];
    }
    int lane = tid & 63;
    int wvu = __builtin_amdgcn_readfirstlane(tid >> 6);
    int k = lane;
    float w2k = w2[k];
    float uacc = b1[k];
    float b20 = b2[0];
    __syncthreads();
    float reacc[11];
    #pragma unroll
    for (int cc = 0; cc < 11; ++cc) reacc[cc] = 0.f;
    #pragma unroll 2
    for (int chunk = 0; chunk < 8; ++chunk){
      float w1u[16], w1r[16];
      #pragma unroll
      for (int j = 0; j < 16; ++j){
        w1u[j] = w1[(chunk*16 + j)*64 + k];
        w1r[j] = w1[(128 + chunk*16 + j)*64 + k];
      }
      {
        const float4* ea = (const float4*)(sm + a*128 + chunk*16);
        #pragma unroll
        for (int t = 0; t < 4; ++t){
          float4 e = ea[t];
          uacc = fmaf(e.x, w1u[t*4+0], uacc);
          uacc = fmaf(e.y, w1u[t*4+1], uacc);
          uacc = fmaf(e.z, w1u[t*4+2], uacc);
          uacc = fmaf(e.w, w1u[t*4+3], uacc);
        }
      }
      #pragma unroll
      for (int cc = 0; cc < 11; ++cc){
        int c = wvu + 4*cc;
        if (c < 42){
          const float4* ec = (const float4*)(sm + c*128 + chunk*16);
          #pragma unroll
          for (int t = 0; t < 4; ++t){
            float4 e = ec[t];
            reacc[cc] = fmaf(e.x, w1r[t*4+0], reacc[cc]);
            reacc[cc] = fmaf(e.y, w1r[t*4+1], reacc[cc]);
            reacc[cc] = fmaf(e.z, w1r[t*4+2], reacc[cc]);
            reacc[cc] = fmaf(e.w, w1r[t*4+3], reacc[cc]);
          }
        }
      }
    }
    #pragma unroll
    for (int cc = 0; cc < 11; ++cc){
      int c = wvu + 4*cc;
      if (c < 43){
        float h  = uacc + ((c < 42) ? reacc[cc] : 0.f);
        float sg = 1.f/(1.f + __expf(-h));
        float sl = h * sg * w2k;
        #pragma unroll
        for (int mk = 1; mk < 64; mk <<= 1) sl += __shfl_xor(sl, mk);
        if (lane == 0)
          ws[OFF_TAU + a*43 + c] = 1.f/(1.f + __expf(-(sl + b20)));
      }
    }
  } else if (blk < 85){
    int c = blk - 42;
    float* s_p0 = sm;
    float* s_p1 = sm + 128;
    float* s_ve = sm + 256;
    int d = tid & 127, h = tid >> 7;
    {
      float acc = (h == 0) ? wv_b[d] : 0.f;
      if (c < 42){
        const float* ec = emb + c*128 + h*64;
        const float* wp = wv_w + (h*64)*128 + d;
        #pragma unroll 8
        for (int i = 0; i < 64; ++i) acc = fmaf(ec[i], wp[i*128], acc);
      }
      (h ? s_p1 : s_p0)[d] = acc;
    }
    __syncthreads();
    if (h == 0) s_ve[d] = s_p0[d] + s_p1[d];
    __syncthreads();
    {
      float acc = 0.f;
      const float* vp = s_ve + h*64;
      const float* mp = mg_w + (128 + h*64)*128 + d;
      #pragma unroll 8
      for (int i = 0; i < 64; ++i) acc = fmaf(vp[i], mp[i*128], acc);
      (h ? s_p1 : s_p0)[d] = acc;
    }
    __syncthreads();
    if (h == 0){
      float vm = s_p0[d] + s_p1[d];
      wbu[(d>>4)*1536 + (d&15)*96 + c] = (ushort)f2b(vm);
    }
  } else if (blk < 127){
    int a = blk - 85;
    float* s_p0 = sm;
    float* s_p1 = sm + 128;
    int d = tid & 127, h = tid >> 7;
    {
      float acc = (h == 0) ? mg_b[d] : 0.f;
      const float* ea = emb + a*128 + h*64;
      const float* mp = mg_w + (h*64)*128 + d;
      #pragma unroll 8
      for (int i = 0; i < 64; ++i) acc = fmaf(ea[i], mp[i*128], acc);
      (h ? s_p1 : s_p0)[d] = acc;
    }
    __syncthreads();
    if (h == 0){
      float ya = s_p0[d] + s_p1[d];
      wbu[(d>>4)*1536 + (d&15)*96 + (43+a)] = (ushort)f2b(ya);
    }
  } else {
    ushort* hbu = (ushort*)(ws + OFF_HB);
    for (int i2 = tid; i2 < 6144; i2 += 256){
      int f = i2 >> 9, ln = (i2 >> 3) & 63, j = i2 & 7;
      int n2 = f >> 2, cc = f & 3;
      int kk = cc*32 + (ln>>4)*8 + j;
      int col = n2*16 + (ln & 15);
      float v = (col < NVOC) ? head_w[kk*NVOC + col] : 0.f;
      hbu[i2] = (ushort)f2b(v);
    }
    for (int i = tid; i < 1408; i += 256){
      int n = i/176, rem = i%176, col = rem/11, kk = 85 + rem%11;
      wbu[n*1536 + col*96 + kk] = 0;
    }
  }
}

// Main (round-5 body) + REP idempotent repeats for measurement. Barrier hoisted
// before the rep loop; each rep is fully wave-local and overwrites identical output.
__global__ __launch_bounds__(256) void k_main(const int* __restrict__ ids,
    const float* __restrict__ ln_g, const float* __restrict__ ln_b,
    const float* __restrict__ head_b, const float* __restrict__ ws,
    float* __restrict__ out){
  __shared__ __align__(16) ushort s_wb[12288];
  __shared__ __align__(16) float  s_T[4][1600];
  __shared__ int s_ids[4][32];

  int tid = threadIdx.x, wv = tid >> 6, lane = tid & 63;
  int r = lane & 15, q = lane >> 4;
  int base = blockIdx.x*64 + wv*16;

  {
    const float4* s2 = (const float4*)(ws + OFF_WB);
    float4* d2 = (float4*)s_wb;
    #pragma unroll
    for (int jj = 0; jj < 6; ++jj){ int i = tid + jj*256; d2[i] = s2[i]; }
  }
  if (lane < 32){
    int v;
    if ((base & (T_SEQ-1)) == 0 && lane < 16) v = NVOC;
    else v = ids[base - 16 + lane];
    s_ids[wv][lane] = v;
  }
  short8 HBf[3][4];
  {
    const ushort* hbsrc = (const ushort*)(ws + OFF_HB);
    #pragma unroll
    for (int n2 = 0; n2 < 3; ++n2)
      #pragma unroll
      for (int c = 0; c < 4; ++c)
        HBf[n2][c] = *(const short8*)&hbsrc[((n2*4 + c)*64 + lane)*8];
  }
  float gd[8], bd[8];
  #pragma unroll
  for (int n = 0; n < 8; ++n){ gd[n] = ln_g[n*16 + r]; bd[n] = ln_b[n*16 + r]; }
  float hb[3];
  #pragma unroll
  for (int n2 = 0; n2 < 3; ++n2){ int col = n2*16 + r; hb[n2] = (col < NVOC) ? head_b[col] : 0.f; }
  __syncthreads();                               // wb staged by all waves

  float* T = s_T[wv];
  for (int rep = 0; rep < REP; ++rep){
    // zero this wave's T region (400 float4)
    {
      float4 z; z.x = z.y = z.z = z.w = 0.f;
      float4* t4 = (float4*)T;
      #pragma unroll
      for (int i = 0; i < 7; ++i){ int idx = lane + i*64; if (idx < 400) t4[idx] = z; }
    }
    int a = s_ids[wv][16 + r];
    const float* tau_g = ws + OFF_TAU;
    #pragma unroll
    for (int m = 0; m < 4; ++m){
      int w = q*4 + m;
      int c = s_ids[wv][r + 15 - w];
      float tv = tau_g[a*43 + c];
      atomicAdd(&T[r*100 + c], tv);
    }
    if (q == 0) T[r*100 + 43 + a] = 1.0f;
    __asm__ volatile("s_waitcnt lgkmcnt(0)" ::: "memory");

    short8 A1[3];
    #pragma unroll
    for (int ct = 0; ct < 3; ++ct){
      const float4* p = (const float4*)&T[r*100 + ct*32 + q*8];
      float4 u0 = p[0], u1 = p[1];
      short8 v;
      v[0]=f2b(u0.x); v[1]=f2b(u0.y); v[2]=f2b(u0.z); v[3]=f2b(u0.w);
      v[4]=f2b(u1.x); v[5]=f2b(u1.y); v[6]=f2b(u1.z); v[7]=f2b(u1.w);
      A1[ct] = v;
    }

    f32x4 accm[8];
    #pragma unroll
    for (int n = 0; n < 8; ++n){ accm[n][0]=0.f; accm[n][1]=0.f; accm[n][2]=0.f; accm[n][3]=0.f; }
    #pragma unroll
    for (int ct = 0; ct < 3; ++ct){
      #pragma unroll
      for (int n = 0; n < 8; ++n){
        short8 b = *(const short8*)&s_wb[n*1536 + r*96 + ct*32 + q*8];
        accm[n] = __builtin_amdgcn_mfma_f32_16x16x32_bf16(A1[ct], b, accm[n], 0, 0, 0);
      }
    }

    ushort* sY = (ushort*)T;                     // Y[16][136] bf16 (overlay)
    #pragma unroll
    for (int reg = 0; reg < 4; ++reg){
      float s1 = 0.f, s2 = 0.f;
      #pragma unroll
      for (int n = 0; n < 8; ++n){ float y = accm[n][reg]; s1 += y; s2 = fmaf(y, y, s2); }
      #pragma unroll
      for (int mk = 1; mk < 16; mk <<= 1){ s1 += __shfl_xor(s1, mk); s2 += __shfl_xor(s2, mk); }
      float mu  = s1 * (1.f/128.f);
      float var = s2 * (1.f/128.f) - mu*mu;
      float rinv = rsqrtf(var + 1e-5f);
      int tok = base + q*4 + reg;
      int m12 = ((tok & (T_SEQ-1)) + 8) % 12;
      float sc = fmaf(0.15f, __sinf((float)m12 * 0.52359877559829887f), 1.0f);
      float A_ = rinv * sc;
      #pragma unroll
      for (int n = 0; n < 8; ++n){
        float yl = (accm[n][reg] - mu) * A_;
        float o  = fmaf(yl, gd[n], bd[n]*sc);
        sY[(q*4 + reg)*136 + n*16 + r] = (ushort)f2b(o);
      }
    }

    f32x4 acch[3];
    #pragma unroll
    for (int n2 = 0; n2 < 3; ++n2){ acch[n2][0]=0.f; acch[n2][1]=0.f; acch[n2][2]=0.f; acch[n2][3]=0.f; }
    short8 A2[4];
    #pragma unroll
    for (int c = 0; c < 4; ++c)
      A2[c] = *(const short8*)&sY[r*136 + c*32 + q*8];
    #pragma unroll
    for (int c = 0; c < 4; ++c){
      #pragma unroll
      for (int n2 = 0; n2 < 3; ++n2)
        acch[n2] = __builtin_amdgcn_mfma_f32_16x16x32_bf16(A2[c], HBf[n2][c], acch[n2], 0, 0, 0);
    }
    #pragma unroll
    for (int n2 = 0; n2 < 3; ++n2){
      int col = n2*16 + r;
      if (col < NVOC){
        #pragma unroll
        for (int reg = 0; reg < 4; ++reg){
          int tok = base + q*4 + reg;
          out[tok*NVOC + col] = acch[n2][reg] + hb[n2];
        }
      }
    }
    __asm__ volatile("" ::: "memory");   // keep reps ordered, no cross-rep folding
  }
}

extern "C" void kernel_launch(void* const* d_in, const int* in_sizes, int n_in,
                              void* d_out, int out_size, void* d_ws, size_t ws_size,
                              hipStream_t stream){
  const int*   ids    = (const int*)  d_in[0];
  const float* emb    = (const float*)d_in[1];
  const float* w1     = (const float*)d_in[2];
  const float* b1     = (const float*)d_in[3];
  const float* w2     = (const float*)d_in[4];
  const float* b2     = (const float*)d_in[5];
  const float* wv_w   = (const float*)d_in[6];
  const float* wv_b   = (const float*)d_in[7];
  const float* mg_w   = (const float*)d_in[8];
  const float* mg_b   = (const float*)d_in[9];
  const float* ln_g   = (const float*)d_in[10];
  const float* ln_b   = (const float*)d_in[11];
  const float* head_w = (const float*)d_in[12];
  const float* head_b = (const float*)d_in[13];
  float* ws  = (float*)d_ws;
  float* out = (float*)d_out;
  k_pre <<<dim3(128), dim3(256), 0, stream>>>(emb, w1, b1, w2, b2, wv_w, wv_b,
                                              mg_w, mg_b, head_w, ws);
  k_main<<<dim3(512), dim3(256), 0, stream>>>(ids, ln_g, ln_b, head_b, ws, out);
}

// Round 7
// 29.853 us; speedup vs baseline: 1.8122x; 1.8122x over previous
//
#include <hip/hip_runtime.h>
#include <hip/hip_bf16.h>
#include <math.h>

typedef __attribute__((ext_vector_type(8))) short short8;
typedef __attribute__((ext_vector_type(4))) float f32x4;

#define T_SEQ 2048
#define NVOC 42

// ws float offsets
#define OFF_TAU 0        // 42*43 = 1806 f32
#define OFF_WB  1808     // u16[24 frag][64 lane][8] = 12288 u16 = 6144 f -> 7952
#define OFF_ZB  7952     // u16[9 frag][64 lane][8]  = 4608 u16  = 2304 f -> 10256
#define OFF_SB  10256    // f32[3][48]: hs | bH | head_b(padded) -> 10400

static __device__ __forceinline__ short f2b(float x){
  __hip_bfloat16 h = __float2bfloat16(x);
  return *reinterpret_cast<short*>(&h);
}

// Fused precompute, 128 blocks x 256 threads, block-local deps only.
//  blocks 0..41   : tau row a (w1 reg-cached, emb via LDS broadcast, shfl-reduce)
//  blocks 42..84  : c -> ve -> vm -> wb frag row k=c, zw row k=c
//  blocks 85..126 : a -> ya -> wb frag row k=43+a, zw row k=43+a
//  block 127      : SB table (hs, bH, head_b) + zero wb/zb rows k=85..95
__global__ __launch_bounds__(256) void k_pre(const float* __restrict__ emb,
    const float* __restrict__ w1, const float* __restrict__ b1,
    const float* __restrict__ w2, const float* __restrict__ b2,
    const float* __restrict__ wv_w, const float* __restrict__ wv_b,
    const float* __restrict__ mg_w, const float* __restrict__ mg_b,
    const float* __restrict__ head_w, const float* __restrict__ head_b,
    const float* __restrict__ ln_g, const float* __restrict__ ln_b,
    float* __restrict__ ws){
  __shared__ __align__(16) float sm[5376];
  int blk = blockIdx.x, tid = threadIdx.x;
  ushort* wbu = (ushort*)(ws + OFF_WB);
  ushort* zbu = (ushort*)(ws + OFF_ZB);
  if (blk < 42){
    int a = blk;
    {
      float4* d4 = (float4*)sm;
      const float4* e4 = (const float4*)emb;
      for (int i = tid; i < 1344; i += 256) d4[i] = e4[i];
    }
    int lane = tid & 63;
    int wvu = __builtin_amdgcn_readfirstlane(tid >> 6);
    int k = lane;
    float w2k = w2[k];
    float uacc = b1[k];
    float b20 = b2[0];
    __syncthreads();
    float reacc[11];
    #pragma unroll
    for (int cc = 0; cc < 11; ++cc) reacc[cc] = 0.f;
    #pragma unroll 2
    for (int chunk = 0; chunk < 8; ++chunk){
      float w1u[16], w1r[16];
      #pragma unroll
      for (int j = 0; j < 16; ++j){
        w1u[j] = w1[(chunk*16 + j)*64 + k];
        w1r[j] = w1[(128 + chunk*16 + j)*64 + k];
      }
      {
        const float4* ea = (const float4*)(sm + a*128 + chunk*16);
        #pragma unroll
        for (int t = 0; t < 4; ++t){
          float4 e = ea[t];
          uacc = fmaf(e.x, w1u[t*4+0], uacc);
          uacc = fmaf(e.y, w1u[t*4+1], uacc);
          uacc = fmaf(e.z, w1u[t*4+2], uacc);
          uacc = fmaf(e.w, w1u[t*4+3], uacc);
        }
      }
      #pragma unroll
      for (int cc = 0; cc < 11; ++cc){
        int c = wvu + 4*cc;
        if (c < 42){
          const float4* ec = (const float4*)(sm + c*128 + chunk*16);
          #pragma unroll
          for (int t = 0; t < 4; ++t){
            float4 e = ec[t];
            reacc[cc] = fmaf(e.x, w1r[t*4+0], reacc[cc]);
            reacc[cc] = fmaf(e.y, w1r[t*4+1], reacc[cc]);
            reacc[cc] = fmaf(e.z, w1r[t*4+2], reacc[cc]);
            reacc[cc] = fmaf(e.w, w1r[t*4+3], reacc[cc]);
          }
        }
      }
    }
    #pragma unroll
    for (int cc = 0; cc < 11; ++cc){
      int c = wvu + 4*cc;
      if (c < 43){
        float h  = uacc + ((c < 42) ? reacc[cc] : 0.f);
        float sg = 1.f/(1.f + __expf(-h));
        float sl = h * sg * w2k;
        #pragma unroll
        for (int mk = 1; mk < 64; mk <<= 1) sl += __shfl_xor(sl, mk);
        if (lane == 0)
          ws[OFF_TAU + a*43 + c] = 1.f/(1.f + __expf(-(sl + b20)));
      }
    }
  } else if (blk < 85){
    int c = blk - 42;                          // 0..42 (42 == zero-padded neighbor)
    float* s_p0 = sm;
    float* s_p1 = sm + 128;
    float* s_ve = sm + 256;
    float* s_gv = sm + 384;
    float* s_pt = sm + 512;                    // [4][48]
    int d = tid & 127, h = tid >> 7;
    {
      float a0 = (h == 0) ? wv_b[d] : 0.f, a1 = 0.f;
      if (c < 42){
        const float* ec = emb + c*128 + h*64;
        const float* wp = wv_w + (h*64)*128 + d;
        #pragma unroll 8
        for (int i = 0; i < 32; ++i) a0 = fmaf(ec[i], wp[i*128], a0);
        #pragma unroll 8
        for (int i = 32; i < 64; ++i) a1 = fmaf(ec[i], wp[i*128], a1);
      }
      (h ? s_p1 : s_p0)[d] = a0 + a1;
    }
    __syncthreads();
    if (h == 0) s_ve[d] = s_p0[d] + s_p1[d];
    __syncthreads();
    {
      float a0 = 0.f, a1 = 0.f;
      const float* vp = s_ve + h*64;
      const float* mp = mg_w + (128 + h*64)*128 + d;
      #pragma unroll 8
      for (int i = 0; i < 32; ++i) a0 = fmaf(vp[i], mp[i*128], a0);
      #pragma unroll 8
      for (int i = 32; i < 64; ++i) a1 = fmaf(vp[i], mp[i*128], a1);
      (h ? s_p1 : s_p0)[d] = a0 + a1;
    }
    __syncthreads();
    if (h == 0){
      float vm = s_p0[d] + s_p1[d];
      s_gv[d] = vm * ln_g[d];
      int k = c;
      wbu[(((d>>4)*3 + (k>>5))*64 + (((k>>3)&3)*16 + (d&15)))*8 + (k&7)] = (ushort)f2b(vm);
    }
    __syncthreads();
    if (tid < 192){
      int c2 = tid % 48, seg = tid / 48;
      float zp = 0.f;
      if (c2 < NVOC){
        const float* hp = head_w + c2;
        const float* gp = s_gv + seg*32;
        #pragma unroll 8
        for (int i = 0; i < 32; ++i) zp = fmaf(gp[i], hp[(seg*32 + i)*NVOC], zp);
      }
      s_pt[seg*48 + c2] = zp;
    }
    __syncthreads();
    if (tid < 48){
      float zw = s_pt[tid] + s_pt[48+tid] + s_pt[96+tid] + s_pt[144+tid];
      int k = c;
      zbu[(((tid>>4)*3 + (k>>5))*64 + (((k>>3)&3)*16 + (tid&15)))*8 + (k&7)] = (ushort)f2b(zw);
    }
  } else if (blk < 127){
    int a = blk - 85;
    float* s_p0 = sm;
    float* s_p1 = sm + 128;
    float* s_gv = sm + 384;
    float* s_pt = sm + 512;
    int d = tid & 127, h = tid >> 7;
    {
      float a0 = (h == 0) ? mg_b[d] : 0.f, a1 = 0.f;
      const float* ea = emb + a*128 + h*64;
      const float* mp = mg_w + (h*64)*128 + d;
      #pragma unroll 8
      for (int i = 0; i < 32; ++i) a0 = fmaf(ea[i], mp[i*128], a0);
      #pragma unroll 8
      for (int i = 32; i < 64; ++i) a1 = fmaf(ea[i], mp[i*128], a1);
      (h ? s_p1 : s_p0)[d] = a0 + a1;
    }
    __syncthreads();
    if (h == 0){
      float ya = s_p0[d] + s_p1[d];
      s_gv[d] = ya * ln_g[d];
      int k = 43 + a;
      wbu[(((d>>4)*3 + (k>>5))*64 + (((k>>3)&3)*16 + (d&15)))*8 + (k&7)] = (ushort)f2b(ya);
    }
    __syncthreads();
    if (tid < 192){
      int c2 = tid % 48, seg = tid / 48;
      float zp = 0.f;
      if (c2 < NVOC){
        const float* hp = head_w + c2;
        const float* gp = s_gv + seg*32;
        #pragma unroll 8
        for (int i = 0; i < 32; ++i) zp = fmaf(gp[i], hp[(seg*32 + i)*NVOC], zp);
      }
      s_pt[seg*48 + c2] = zp;
    }
    __syncthreads();
    if (tid < 48){
      float zw = s_pt[tid] + s_pt[48+tid] + s_pt[96+tid] + s_pt[144+tid];
      int k = 43 + a;
      zbu[(((tid>>4)*3 + (k>>5))*64 + (((k>>3)&3)*16 + (tid&15)))*8 + (k&7)] = (ushort)f2b(zw);
    }
  } else {
    if (tid < 96){
      int c2 = tid % 48, which = tid / 48;
      float s = 0.f;
      if (c2 < NVOC){
        const float* hp = head_w + c2;
        const float* gp = which ? ln_b : ln_g;
        #pragma unroll 8
        for (int i = 0; i < 128; ++i) s = fmaf(gp[i], hp[i*NVOC], s);
      }
      ws[OFF_SB + which*48 + c2] = s;
    } else if (tid < 144){
      int c2 = tid - 96;
      ws[OFF_SB + 96 + c2] = (c2 < NVOC) ? head_b[c2] : 0.f;
    }
    for (int i = tid; i < 1408; i += 256){
      int n = i/176, rem = i%176, k = 85 + rem/16, col = rem%16;
      wbu[((n*3 + 2)*64 + (((k>>3)&3)*16 + col))*8 + (k&7)] = 0;
    }
    for (int i = tid; i < 528; i += 256){
      int n2 = i/176, rem = i%176, k = 85 + rem/16, col = rem%16;
      zbu[((n2*3 + 2)*64 + (((k>>3)&3)*16 + col))*8 + (k&7)] = 0;
    }
  }
}

// Main: per wave 16 tokens, fully wave-independent, ZERO barriers.
// T built via LDS atomics; B-frags (wb,zb) read from global frag-major tables
// (L1/L2-hot, every wave reads identical coalesced 1KB frags); ids via shfl;
// 24 stats-MFMAs + 9 z-MFMAs off the same A1; LN stats in f32; folded epilogue.
__global__ __launch_bounds__(256) void k_main(const int* __restrict__ ids,
    const float* __restrict__ ws, float* __restrict__ out){
  __shared__ __align__(16) float s_T[4][1600];
  int tid = threadIdx.x, wv = tid >> 6, lane = tid & 63;
  int r = lane & 15, q = lane >> 4;
  int base = blockIdx.x*64 + wv*16;
  const ushort* wbu = (const ushort*)(ws + OFF_WB);
  const ushort* zbu = (const ushort*)(ws + OFF_ZB);

  // per-lane neighborhood ids (lanes 0..31 carry ids[base-16 .. base+15])
  int l32 = lane & 31;
  int idv = NVOC;
  if (!(((base & (T_SEQ-1)) == 0) && (l32 < 16))) idv = ids[base - 16 + l32];

  // folded epilogue params
  float hs3[3], bh3[3], hb3[3];
  #pragma unroll
  for (int n2 = 0; n2 < 3; ++n2){
    hs3[n2] = ws[OFF_SB + n2*16 + r];
    bh3[n2] = ws[OFF_SB + 48 + n2*16 + r];
    hb3[n2] = ws[OFF_SB + 96 + n2*16 + r];
  }

  // build T (wave-local): zero, scatter tau via ds_add, select ya row
  float* T = s_T[wv];
  {
    float4 z; z.x=z.y=z.z=z.w=0.f;
    float4* t4 = (float4*)T;
    #pragma unroll
    for (int i = 0; i < 7; ++i){ int idx = lane + i*64; if (idx < 400) t4[idx] = z; }
  }
  int a = __shfl(idv, 16 + r);
  const float* tau_g = ws + OFF_TAU;
  #pragma unroll
  for (int m = 0; m < 4; ++m){
    int w = q*4 + m;
    int c = __shfl(idv, r + 15 - w);
    float tv = tau_g[a*43 + c];
    atomicAdd(&T[r*100 + c], tv);
  }
  if (q == 0) T[r*100 + 43 + a] = 1.0f;
  __asm__ volatile("s_waitcnt lgkmcnt(0)" ::: "memory");

  // A1 fragments from T
  short8 A1[3];
  #pragma unroll
  for (int ct = 0; ct < 3; ++ct){
    const float4* p = (const float4*)&T[r*100 + ct*32 + q*8];
    float4 u0 = p[0], u1 = p[1];
    short8 v;
    v[0]=f2b(u0.x); v[1]=f2b(u0.y); v[2]=f2b(u0.z); v[3]=f2b(u0.w);
    v[4]=f2b(u1.x); v[5]=f2b(u1.y); v[6]=f2b(u1.z); v[7]=f2b(u1.w);
    A1[ct] = v;
  }

  // stats MFMAs (y = T@W) + z MFMAs (z = T@ZW), B-frags straight from global
  f32x4 accm[8];
  #pragma unroll
  for (int n = 0; n < 8; ++n){ accm[n][0]=0.f; accm[n][1]=0.f; accm[n][2]=0.f; accm[n][3]=0.f; }
  f32x4 zacc[3];
  #pragma unroll
  for (int n2 = 0; n2 < 3; ++n2){ zacc[n2][0]=0.f; zacc[n2][1]=0.f; zacc[n2][2]=0.f; zacc[n2][3]=0.f; }
  #pragma unroll
  for (int ct = 0; ct < 3; ++ct){
    #pragma unroll
    for (int n = 0; n < 8; ++n){
      short8 b = *(const short8*)&wbu[((n*3 + ct)*64 + lane)*8];
      accm[n] = __builtin_amdgcn_mfma_f32_16x16x32_bf16(A1[ct], b, accm[n], 0, 0, 0);
    }
    #pragma unroll
    for (int n2 = 0; n2 < 3; ++n2){
      short8 zf = *(const short8*)&zbu[((n2*3 + ct)*64 + lane)*8];
      zacc[n2] = __builtin_amdgcn_mfma_f32_16x16x32_bf16(A1[ct], zf, zacc[n2], 0, 0, 0);
    }
  }

  // LN stats + folded scale/head epilogue
  #pragma unroll
  for (int reg = 0; reg < 4; ++reg){
    float s1 = 0.f, s2 = 0.f;
    #pragma unroll
    for (int n = 0; n < 8; ++n){ float y = accm[n][reg]; s1 += y; s2 = fmaf(y, y, s2); }
    #pragma unroll
    for (int mk = 1; mk < 16; mk <<= 1){ s1 += __shfl_xor(s1, mk); s2 += __shfl_xor(s2, mk); }
    float mu  = s1 * (1.f/128.f);
    float var = s2 * (1.f/128.f) - mu*mu;
    float rinv = rsqrtf(var + 1e-5f);
    int tok = base + q*4 + reg;
    int m12 = ((tok & (T_SEQ-1)) + 8) % 12;
    float sc = fmaf(0.15f, __sinf((float)m12 * 0.52359877559829887f), 1.0f);
    float sr  = sc * rinv;
    float srm = sr * mu;
    #pragma unroll
    for (int n2 = 0; n2 < 3; ++n2){
      int col = n2*16 + r;
      if (col < NVOC){
        float o = fmaf(sr, zacc[n2][reg], fmaf(-srm, hs3[n2], fmaf(sc, bh3[n2], hb3[n2])));
        out[tok*NVOC + col] = o;
      }
    }
  }
}

extern "C" void kernel_launch(void* const* d_in, const int* in_sizes, int n_in,
                              void* d_out, int out_size, void* d_ws, size_t ws_size,
                              hipStream_t stream){
  const int*   ids    = (const int*)  d_in[0];
  const float* emb    = (const float*)d_in[1];
  const float* w1     = (const float*)d_in[2];
  const float* b1     = (const float*)d_in[3];
  const float* w2     = (const float*)d_in[4];
  const float* b2     = (const float*)d_in[5];
  const float* wv_w   = (const float*)d_in[6];
  const float* wv_b   = (const float*)d_in[7];
  const float* mg_w   = (const float*)d_in[8];
  const float* mg_b   = (const float*)d_in[9];
  const float* ln_g   = (const float*)d_in[10];
  const float* ln_b   = (const float*)d_in[11];
  const float* head_w = (const float*)d_in[12];
  const float* head_b = (const float*)d_in[13];
  float* ws  = (float*)d_ws;
  float* out = (float*)d_out;
  k_pre <<<dim3(128), dim3(256), 0, stream>>>(emb, w1, b1, w2, b2, wv_w, wv_b,
                                              mg_w, mg_b, head_w, head_b, ln_g, ln_b, ws);
  k_main<<<dim3(512), dim3(256), 0, stream>>>(ids, ws, out);
}

// Round 8
// 29.250 us; speedup vs baseline: 1.8495x; 1.0206x over previous
//
#include <hip/hip_runtime.h>
#include <hip/hip_bf16.h>
#include <math.h>

typedef __attribute__((ext_vector_type(8))) short short8;
typedef __attribute__((ext_vector_type(4))) float f32x4;

#define T_SEQ 2048
#define NVOC 42

// ws float offsets
#define OFF_TAU 0        // 42*43 = 1806 f32
#define OFF_WB  1808     // u16[24 frag][64 lane][8] = 12288 u16 = 6144 f -> 7952
#define OFF_ZB  7952     // u16[9 frag][64 lane][8]  = 4608 u16  = 2304 f -> 10256
#define OFF_SB  10256    // f32[3][48]: hs | bH | head_b(padded) -> 10400

static __device__ __forceinline__ short f2b(float x){
  __hip_bfloat16 h = __float2bfloat16(x);
  return *reinterpret_cast<short*>(&h);
}

// Fused precompute, 128 blocks x 256 threads, block-local deps only.
// Deep load queues: all independent global loads issued before first use.
//  blocks 0..41   : tau row a (w1 double-buffered reg chunks, emb via LDS broadcast)
//  blocks 42..84  : c -> ve -> vm -> wb row k=c ; zw -> zb row k=c (head_w in LDS)
//  blocks 85..126 : a -> ya -> wb row k=43+a ; zw -> zb row k=43+a
//  block 127      : SB table (hs, bH, head_b) + zero wb/zb rows k=85..95
__global__ __launch_bounds__(256) void k_pre(const float* __restrict__ emb,
    const float* __restrict__ w1, const float* __restrict__ b1,
    const float* __restrict__ w2, const float* __restrict__ b2,
    const float* __restrict__ wv_w, const float* __restrict__ wv_b,
    const float* __restrict__ mg_w, const float* __restrict__ mg_b,
    const float* __restrict__ head_w, const float* __restrict__ head_b,
    const float* __restrict__ ln_g, const float* __restrict__ ln_b,
    float* __restrict__ ws){
  __shared__ __align__(16) float sm[5888];
  int blk = blockIdx.x, tid = threadIdx.x;
  ushort* wbu = (ushort*)(ws + OFF_WB);
  ushort* zbu = (ushort*)(ws + OFF_ZB);
  if (blk < 42){
    int a = blk;
    {
      float4* d4 = (float4*)sm;
      const float4* e4 = (const float4*)emb;
      for (int i = tid; i < 1344; i += 256) d4[i] = e4[i];
    }
    int lane = tid & 63;
    int wvu = __builtin_amdgcn_readfirstlane(tid >> 6);
    int k = lane;
    float w2k = w2[k];
    float uacc = b1[k];
    float b20 = b2[0];
    __syncthreads();
    float reacc[11];
    #pragma unroll
    for (int cc = 0; cc < 11; ++cc) reacc[cc] = 0.f;

    float wuA[16], wrA[16], wuB[16], wrB[16];
    auto LOADW = [&](int ch, float* wu, float* wr){
      #pragma unroll
      for (int j = 0; j < 16; ++j){
        wu[j] = w1[(ch*16 + j)*64 + k];
        wr[j] = w1[(128 + ch*16 + j)*64 + k];
      }
    };
    auto COMPUTE = [&](int ch, const float* wu, const float* wr){
      {
        const float4* ea = (const float4*)(sm + a*128 + ch*16);
        #pragma unroll
        for (int t = 0; t < 4; ++t){
          float4 e = ea[t];
          uacc = fmaf(e.x, wu[t*4+0], uacc);
          uacc = fmaf(e.y, wu[t*4+1], uacc);
          uacc = fmaf(e.z, wu[t*4+2], uacc);
          uacc = fmaf(e.w, wu[t*4+3], uacc);
        }
      }
      #pragma unroll
      for (int cc = 0; cc < 11; ++cc){
        int c = wvu + 4*cc;
        if (c < 42){
          const float4* ec = (const float4*)(sm + c*128 + ch*16);
          #pragma unroll
          for (int t = 0; t < 4; ++t){
            float4 e = ec[t];
            reacc[cc] = fmaf(e.x, wr[t*4+0], reacc[cc]);
            reacc[cc] = fmaf(e.y, wr[t*4+1], reacc[cc]);
            reacc[cc] = fmaf(e.z, wr[t*4+2], reacc[cc]);
            reacc[cc] = fmaf(e.w, wr[t*4+3], reacc[cc]);
          }
        }
      }
    };
    LOADW(0, wuA, wrA);
    #pragma unroll
    for (int ch2 = 0; ch2 < 4; ++ch2){
      LOADW(2*ch2+1, wuB, wrB);
      COMPUTE(2*ch2, wuA, wrA);
      if (ch2 < 3) LOADW(2*ch2+2, wuA, wrA);
      COMPUTE(2*ch2+1, wuB, wrB);
    }
    #pragma unroll
    for (int cc = 0; cc < 11; ++cc){
      int c = wvu + 4*cc;
      if (c < 43){
        float h  = uacc + ((c < 42) ? reacc[cc] : 0.f);
        float sg = 1.f/(1.f + __expf(-h));
        float sl = h * sg * w2k;
        #pragma unroll
        for (int mk = 1; mk < 64; mk <<= 1) sl += __shfl_xor(sl, mk);
        if (lane == 0)
          ws[OFF_TAU + a*43 + c] = 1.f/(1.f + __expf(-(sl + b20)));
      }
    }
  } else if (blk < 85){
    int c = blk - 42;                          // 0..42 (42 == zero-padded neighbor)
    float* s_p0 = sm;                          // [128]
    float* s_p1 = sm + 128;                    // [128]
    float* s_ve = sm + 256;                    // [128]
    float* s_gv = sm + 384;                    // [128]
    float* s_hw = sm + 512;                    // [5376] = head_w linear [128][42]
    int d = tid & 127, h = tid >> 7;
    // issue ALL independent loads first: head_w staging, stage-1, stage-2
    float hwreg[21];
    #pragma unroll
    for (int t = 0; t < 21; ++t) hwreg[t] = head_w[tid + t*256];
    float r1[64], r2[64];
    const float* wp = wv_w + (h*64)*128 + d;
    const float* mp = mg_w + (128 + h*64)*128 + d;
    if (c < 42){
      #pragma unroll
      for (int i = 0; i < 64; ++i) r1[i] = wp[i*128];
    }
    #pragma unroll
    for (int i = 0; i < 64; ++i) r2[i] = mp[i*128];
    #pragma unroll
    for (int t = 0; t < 21; ++t) s_hw[tid + t*256] = hwreg[t];
    // stage 1: ve
    float a0 = (h == 0) ? wv_b[d] : 0.f, a1 = 0.f;
    if (c < 42){
      const float* ec = emb + c*128 + h*64;
      #pragma unroll
      for (int i = 0; i < 32; ++i) a0 = fmaf(ec[i], r1[i], a0);
      #pragma unroll
      for (int i = 32; i < 64; ++i) a1 = fmaf(ec[i], r1[i], a1);
    }
    (h ? s_p1 : s_p0)[d] = a0 + a1;
    __syncthreads();
    if (h == 0) s_ve[d] = s_p0[d] + s_p1[d];
    __syncthreads();
    // stage 2: vm (r2 already resident)
    {
      float b0 = 0.f, b1v = 0.f;
      const float* vp = s_ve + h*64;
      #pragma unroll
      for (int i = 0; i < 32; ++i) b0 = fmaf(vp[i], r2[i], b0);
      #pragma unroll
      for (int i = 32; i < 64; ++i) b1v = fmaf(vp[i], r2[i], b1v);
      (h ? s_p1 : s_p0)[d] = b0 + b1v;
    }
    __syncthreads();
    if (h == 0){
      float vm = s_p0[d] + s_p1[d];
      s_gv[d] = vm * ln_g[d];
      int k = c;
      wbu[(((d>>4)*3 + (k>>5))*64 + (((k>>3)&3)*16 + (d&15)))*8 + (k&7)] = (ushort)f2b(vm);
    }
    __syncthreads();
    if (tid < 48){
      float zw = 0.f;
      if (tid < NVOC){
        #pragma unroll 8
        for (int dd = 0; dd < 128; ++dd) zw = fmaf(s_gv[dd], s_hw[dd*NVOC + tid], zw);
      }
      int k = c;
      zbu[(((tid>>4)*3 + (k>>5))*64 + (((k>>3)&3)*16 + (tid&15)))*8 + (k&7)] = (ushort)f2b(zw);
    }
  } else if (blk < 127){
    int a = blk - 85;
    float* s_p0 = sm;
    float* s_p1 = sm + 128;
    float* s_gv = sm + 384;
    float* s_hw = sm + 512;
    int d = tid & 127, h = tid >> 7;
    float hwreg[21];
    #pragma unroll
    for (int t = 0; t < 21; ++t) hwreg[t] = head_w[tid + t*256];
    float r1[64];
    const float* mp1 = mg_w + (h*64)*128 + d;
    #pragma unroll
    for (int i = 0; i < 64; ++i) r1[i] = mp1[i*128];
    #pragma unroll
    for (int t = 0; t < 21; ++t) s_hw[tid + t*256] = hwreg[t];
    float a0 = (h == 0) ? mg_b[d] : 0.f, a1 = 0.f;
    {
      const float* ea = emb + a*128 + h*64;
      #pragma unroll
      for (int i = 0; i < 32; ++i) a0 = fmaf(ea[i], r1[i], a0);
      #pragma unroll
      for (int i = 32; i < 64; ++i) a1 = fmaf(ea[i], r1[i], a1);
    }
    (h ? s_p1 : s_p0)[d] = a0 + a1;
    __syncthreads();
    if (h == 0){
      float ya = s_p0[d] + s_p1[d];
      s_gv[d] = ya * ln_g[d];
      int k = 43 + a;
      wbu[(((d>>4)*3 + (k>>5))*64 + (((k>>3)&3)*16 + (d&15)))*8 + (k&7)] = (ushort)f2b(ya);
    }
    __syncthreads();
    if (tid < 48){
      float zw = 0.f;
      if (tid < NVOC){
        #pragma unroll 8
        for (int dd = 0; dd < 128; ++dd) zw = fmaf(s_gv[dd], s_hw[dd*NVOC + tid], zw);
      }
      int k = 43 + a;
      zbu[(((tid>>4)*3 + (k>>5))*64 + (((k>>3)&3)*16 + (tid&15)))*8 + (k&7)] = (ushort)f2b(zw);
    }
  } else {
    if (tid < 96){
      int c2 = tid % 48, which = tid / 48;
      float s = 0.f;
      if (c2 < NVOC){
        const float* hp = head_w + c2;
        const float* gp = which ? ln_b : ln_g;
        #pragma unroll 8
        for (int i = 0; i < 128; ++i) s = fmaf(gp[i], hp[i*NVOC], s);
      }
      ws[OFF_SB + which*48 + c2] = s;
    } else if (tid < 144){
      int c2 = tid - 96;
      ws[OFF_SB + 96 + c2] = (c2 < NVOC) ? head_b[c2] : 0.f;
    }
    for (int i = tid; i < 1408; i += 256){
      int n = i/176, rem = i%176, k = 85 + rem/16, col = rem%16;
      wbu[((n*3 + 2)*64 + (((k>>3)&3)*16 + col))*8 + (k&7)] = 0;
    }
    for (int i = tid; i < 528; i += 256){
      int n2 = i/176, rem = i%176, k = 85 + rem/16, col = rem%16;
      zbu[((n2*3 + 2)*64 + (((k>>3)&3)*16 + col))*8 + (k&7)] = 0;
    }
  }
}

// Main: per wave 16 tokens, fully wave-independent, ZERO barriers. (identical to R7)
__global__ __launch_bounds__(256) void k_main(const int* __restrict__ ids,
    const float* __restrict__ ws, float* __restrict__ out){
  __shared__ __align__(16) float s_T[4][1600];
  int tid = threadIdx.x, wv = tid >> 6, lane = tid & 63;
  int r = lane & 15, q = lane >> 4;
  int base = blockIdx.x*64 + wv*16;
  const ushort* wbu = (const ushort*)(ws + OFF_WB);
  const ushort* zbu = (const ushort*)(ws + OFF_ZB);

  int l32 = lane & 31;
  int idv = NVOC;
  if (!(((base & (T_SEQ-1)) == 0) && (l32 < 16))) idv = ids[base - 16 + l32];

  float hs3[3], bh3[3], hb3[3];
  #pragma unroll
  for (int n2 = 0; n2 < 3; ++n2){
    hs3[n2] = ws[OFF_SB + n2*16 + r];
    bh3[n2] = ws[OFF_SB + 48 + n2*16 + r];
    hb3[n2] = ws[OFF_SB + 96 + n2*16 + r];
  }

  float* T = s_T[wv];
  {
    float4 z; z.x=z.y=z.z=z.w=0.f;
    float4* t4 = (float4*)T;
    #pragma unroll
    for (int i = 0; i < 7; ++i){ int idx = lane + i*64; if (idx < 400) t4[idx] = z; }
  }
  int a = __shfl(idv, 16 + r);
  const float* tau_g = ws + OFF_TAU;
  #pragma unroll
  for (int m = 0; m < 4; ++m){
    int w = q*4 + m;
    int c = __shfl(idv, r + 15 - w);
    float tv = tau_g[a*43 + c];
    atomicAdd(&T[r*100 + c], tv);
  }
  if (q == 0) T[r*100 + 43 + a] = 1.0f;
  __asm__ volatile("s_waitcnt lgkmcnt(0)" ::: "memory");

  short8 A1[3];
  #pragma unroll
  for (int ct = 0; ct < 3; ++ct){
    const float4* p = (const float4*)&T[r*100 + ct*32 + q*8];
    float4 u0 = p[0], u1 = p[1];
    short8 v;
    v[0]=f2b(u0.x); v[1]=f2b(u0.y); v[2]=f2b(u0.z); v[3]=f2b(u0.w);
    v[4]=f2b(u1.x); v[5]=f2b(u1.y); v[6]=f2b(u1.z); v[7]=f2b(u1.w);
    A1[ct] = v;
  }

  f32x4 accm[8];
  #pragma unroll
  for (int n = 0; n < 8; ++n){ accm[n][0]=0.f; accm[n][1]=0.f; accm[n][2]=0.f; accm[n][3]=0.f; }
  f32x4 zacc[3];
  #pragma unroll
  for (int n2 = 0; n2 < 3; ++n2){ zacc[n2][0]=0.f; zacc[n2][1]=0.f; zacc[n2][2]=0.f; zacc[n2][3]=0.f; }
  #pragma unroll
  for (int ct = 0; ct < 3; ++ct){
    #pragma unroll
    for (int n = 0; n < 8; ++n){
      short8 b = *(const short8*)&wbu[((n*3 + ct)*64 + lane)*8];
      accm[n] = __builtin_amdgcn_mfma_f32_16x16x32_bf16(A1[ct], b, accm[n], 0, 0, 0);
    }
    #pragma unroll
    for (int n2 = 0; n2 < 3; ++n2){
      short8 zf = *(const short8*)&zbu[((n2*3 + ct)*64 + lane)*8];
      zacc[n2] = __builtin_amdgcn_mfma_f32_16x16x32_bf16(A1[ct], zf, zacc[n2], 0, 0, 0);
    }
  }

  #pragma unroll
  for (int reg = 0; reg < 4; ++reg){
    float s1 = 0.f, s2 = 0.f;
    #pragma unroll
    for (int n = 0; n < 8; ++n){ float y = accm[n][reg]; s1 += y; s2 = fmaf(y, y, s2); }
    #pragma unroll
    for (int mk = 1; mk < 16; mk <<= 1){ s1 += __shfl_xor(s1, mk); s2 += __shfl_xor(s2, mk); }
    float mu  = s1 * (1.f/128.f);
    float var = s2 * (1.f/128.f) - mu*mu;
    float rinv = rsqrtf(var + 1e-5f);
    int tok = base + q*4 + reg;
    int m12 = ((tok & (T_SEQ-1)) + 8) % 12;
    float sc = fmaf(0.15f, __sinf((float)m12 * 0.52359877559829887f), 1.0f);
    float sr  = sc * rinv;
    float srm = sr * mu;
    #pragma unroll
    for (int n2 = 0; n2 < 3; ++n2){
      int col = n2*16 + r;
      if (col < NVOC){
        float o = fmaf(sr, zacc[n2][reg], fmaf(-srm, hs3[n2], fmaf(sc, bh3[n2], hb3[n2])));
        out[tok*NVOC + col] = o;
      }
    }
  }
}

extern "C" void kernel_launch(void* const* d_in, const int* in_sizes, int n_in,
                              void* d_out, int out_size, void* d_ws, size_t ws_size,
                              hipStream_t stream){
  const int*   ids    = (const int*)  d_in[0];
  const float* emb    = (const float*)d_in[1];
  const float* w1     = (const float*)d_in[2];
  const float* b1     = (const float*)d_in[3];
  const float* w2     = (const float*)d_in[4];
  const float* b2     = (const float*)d_in[5];
  const float* wv_w   = (const float*)d_in[6];
  const float* wv_b   = (const float*)d_in[7];
  const float* mg_w   = (const float*)d_in[8];
  const float* mg_b   = (const float*)d_in[9];
  const float* ln_g   = (const float*)d_in[10];
  const float* ln_b   = (const float*)d_in[11];
  const float* head_w = (const float*)d_in[12];
  const float* head_b = (const float*)d_in[13];
  float* ws  = (float*)d_ws;
  float* out = (float*)d_out;
  k_pre <<<dim3(128), dim3(256), 0, stream>>>(emb, w1, b1, w2, b2, wv_w, wv_b,
                                              mg_w, mg_b, head_w, head_b, ln_g, ln_b, ws);
  k_main<<<dim3(512), dim3(256), 0, stream>>>(ids, ws, out);
}